// Round 8
// baseline (286.590 us; speedup 1.0000x reference)
//
#include <hip/hip_runtime.h>
#include <hip/hip_bf16.h>
#include <hip/hip_cooperative_groups.h>
#include <stdint.h>
#include <math.h>

namespace cg = cooperative_groups;

// Problem constants (fixed by setup_inputs)
#define BATCH 8192   // B rows of embeddings
#define DIM   2048   // D feature dim
#define KDIR  512    // K directions
#define NPTS  17     // quadrature points

typedef _Float16 half8  __attribute__((ext_vector_type(8)));
typedef float   floatx4 __attribute__((ext_vector_type(4)));

#define AS1 __attribute__((address_space(1)))
#define AS3 __attribute__((address_space(3)))

__device__ __forceinline__ void g2l16(const void* g, void* l) {
    __builtin_amdgcn_global_load_lds((AS1 void*)(uintptr_t)g, (AS3 void*)l, 16u, 0, 0u);
}

// ---------------------------------------------------------------------------
// K1: fused normalize + transpose (+ zero pp and pecf in low blocks).
__global__ __launch_bounds__(256) void norm_dT(const float* __restrict__ dir,
                                               _Float16* __restrict__ dT,
                                               float* __restrict__ pp,
                                               float* __restrict__ pecf) {
    const int k = blockIdx.x;
    const int t = threadIdx.x;
    if (k < 4) pp[k * 256 + t] = 0.f;                 // pp[1024]
    if (k >= 4 && k < 72) pecf[(k - 4) * 256 + t] = 0.f;  // pecf[17408]

    float v[8];
    float s = 0.f;
    #pragma unroll
    for (int i = 0; i < 8; ++i) {
        v[i] = dir[(size_t)(t * 8 + i) * KDIR + k];
        s = fmaf(v[i], v[i], s);
    }
    for (int off = 32; off > 0; off >>= 1) s += __shfl_down(s, off, 64);
    __shared__ float ws_[4];
    if ((t & 63) == 0) ws_[t >> 6] = s;
    __syncthreads();
    const float inv = 1.0f / fmaxf(sqrtf(ws_[0] + ws_[1] + ws_[2] + ws_[3]), 1e-12f);
    half8 h;
    #pragma unroll
    for (int i = 0; i < 8; ++i) h[i] = (_Float16)(v[i] * inv);
    *(half8*)(dT + (size_t)k * DIM + t * 8) = h;
}

// ---------------------------------------------------------------------------
// K2: embeddings fp32 -> fp16
__global__ __launch_bounds__(256) void cvt_f16(const float* __restrict__ x,
                                               _Float16* __restrict__ y) {
    const size_t i = ((size_t)blockIdx.x * 256 + threadIdx.x) * 8;
    floatx4 a = *(const floatx4*)(x + i);
    floatx4 b = *(const floatx4*)(x + i + 4);
    half8 h;
    h[0] = (_Float16)a[0]; h[1] = (_Float16)a[1];
    h[2] = (_Float16)a[2]; h[3] = (_Float16)a[3];
    h[4] = (_Float16)b[0]; h[5] = (_Float16)b[1];
    h[6] = (_Float16)b[2]; h[7] = (_Float16)b[3];
    *(half8*)(y + i) = h;
}

// ---------------------------------------------------------------------------
// K3: COOPERATIVE mega-kernel: GEMM (R6's measured 45.8us structure, C stores
// dropped — proj never hits memory) + fused stats atomics -> grid.sync ->
// ECF partials straight from acc registers -> grid.sync -> block0 final.
// Grid 64x4 = 256 blocks = 1/CU (LDS 64KB => co-residency structural).
__global__ __launch_bounds__(256) void megak(const _Float16* __restrict__ A,
                                             const _Float16* __restrict__ Bt,
                                             float* __restrict__ pp,
                                             float* __restrict__ pecf,
                                             float* __restrict__ out) {
    __shared__ _Float16 sA[2][2][128 * 32];   // [stage][panel][m][k] 8KB each
    __shared__ _Float16 sB[2][2][128 * 32];

    const int tid  = threadIdx.x;
    const int lane = tid & 63;
    const int wave = tid >> 6;
    const int wm = wave & 1;
    const int wn = wave >> 1;
    const int tm = blockIdx.x * 128;
    const int tn = blockIdx.y * 128;

    const int srow = tid >> 2;
    const int scol = (tid & 3) * 8;
    const _Float16* baseA = A  + (size_t)(tm + srow) * DIM + scol;
    const _Float16* baseB = Bt + (size_t)(tn + srow) * DIM + scol;

#define ISSUE(IT, ST)                                                         \
    do {                                                                      \
        const _Float16* pa = baseA + (IT) * 64;                               \
        const _Float16* pb = baseB + (IT) * 64;                               \
        g2l16(pa,                 (char*)&sA[ST][0][0] + tid * 16);           \
        g2l16(pa + 64 * DIM,      (char*)&sA[ST][0][0] + 4096 + tid * 16);    \
        g2l16(pa + 32,            (char*)&sA[ST][1][0] + tid * 16);           \
        g2l16(pa + 64 * DIM + 32, (char*)&sA[ST][1][0] + 4096 + tid * 16);    \
        g2l16(pb,                 (char*)&sB[ST][0][0] + tid * 16);           \
        g2l16(pb + 64 * DIM,      (char*)&sB[ST][0][0] + 4096 + tid * 16);    \
        g2l16(pb + 32,            (char*)&sB[ST][1][0] + tid * 16);           \
        g2l16(pb + 64 * DIM + 32, (char*)&sB[ST][1][0] + 4096 + tid * 16);    \
    } while (0)

    const floatx4 zero = {0.f, 0.f, 0.f, 0.f};
    floatx4 acc[4][4];
    #pragma unroll
    for (int i = 0; i < 4; ++i)
        #pragma unroll
        for (int j = 0; j < 4; ++j) acc[i][j] = zero;

    const int mrow = lane & 15;
    const int kk   = (lane >> 4) * 8;

    ISSUE(0, 0);

    const int NIT = DIM / 64;                      // 32
    for (int it = 0; it < NIT; ++it) {
        const int s = it & 1;
        if (it + 1 < NIT) {
            ISSUE(it + 1, (it + 1) & 1);
            asm volatile("s_waitcnt vmcnt(8)" ::: "memory");
        } else {
            asm volatile("s_waitcnt vmcnt(0)" ::: "memory");
        }
        asm volatile("s_barrier" ::: "memory");

        half8 a0[4], a1[4], b0[4], b1[4];
        #pragma unroll
        for (int f = 0; f < 4; ++f) {
            a0[f] = *(const half8*)(&sA[s][0][(size_t)(wm * 64 + f * 16 + mrow) * 32 + kk]);
            a1[f] = *(const half8*)(&sA[s][1][(size_t)(wm * 64 + f * 16 + mrow) * 32 + kk]);
            b0[f] = *(const half8*)(&sB[s][0][(size_t)(wn * 64 + f * 16 + mrow) * 32 + kk]);
            b1[f] = *(const half8*)(&sB[s][1][(size_t)(wn * 64 + f * 16 + mrow) * 32 + kk]);
        }
        #pragma unroll
        for (int i = 0; i < 4; ++i)
            #pragma unroll
            for (int j = 0; j < 4; ++j) {
                acc[i][j] = __builtin_amdgcn_mfma_f32_16x16x32_f16(a0[i], b0[j], acc[i][j], 0, 0, 0);
                acc[i][j] = __builtin_amdgcn_mfma_f32_16x16x32_f16(a1[i], b1[j], acc[i][j], 0, 0, 0);
            }
        asm volatile("s_waitcnt lgkmcnt(0)" ::: "memory");
        asm volatile("s_barrier" ::: "memory");
    }
#undef ISSUE

    // fused column stats -> pp (device-scope atomics)
    #pragma unroll
    for (int j = 0; j < 4; ++j) {
        float s = 0.f, q = 0.f;
        #pragma unroll
        for (int i = 0; i < 4; ++i)
            #pragma unroll
            for (int r = 0; r < 4; ++r) {
                float v = acc[i][j][r];
                s += v;
                q = fmaf(v, v, q);
            }
        s += __shfl_down(s, 32, 64); q += __shfl_down(q, 32, 64);
        s += __shfl_down(s, 16, 64); q += __shfl_down(q, 16, 64);
        if (lane < 16) {
            const int col = tn + wn * 64 + j * 16 + lane;
            atomicAdd(&pp[col], s);
            atomicAdd(&pp[KDIR + col], q);
        }
    }

    __threadfence();
    cg::this_grid().sync();

    // per-lane mu/isd for its 4 columns (agent-scope loads; pp is L2/LLC-hot)
    const int cn = lane & 15;
    float mu4[4], isd4[4];
    #pragma unroll
    for (int j = 0; j < 4; ++j) {
        const int col = tn + wn * 64 + j * 16 + cn;
        float s = __hip_atomic_load(&pp[col],        __ATOMIC_RELAXED, __HIP_MEMORY_SCOPE_AGENT);
        float q = __hip_atomic_load(&pp[KDIR + col], __ATOMIC_RELAXED, __HIP_MEMORY_SCOPE_AGENT);
        double m   = (double)s / (double)BATCH;
        double var = ((double)q - (double)BATCH * m * m) / (double)(BATCH - 1);
        mu4[j]  = (float)m;
        isd4[j] = (float)(1.0 / (sqrt(var) + 1e-8));
    }

    // ECF partials straight from acc (angle-addition recurrence, R6 numerics).
    #pragma unroll
    for (int j = 0; j < 4; ++j) {
        float cr[NPTS], ci[NPTS];
        #pragma unroll
        for (int k = 0; k < NPTS; ++k) { cr[k] = 0.f; ci[k] = 0.f; }
        #pragma unroll
        for (int i = 0; i < 4; ++i)
            #pragma unroll
            for (int r = 0; r < 4; ++r) {
                float z = (acc[i][j][r] - mu4[j]) * isd4[j];
                float a = z * (2.0f / 17.0f);
                float s1, c1;
                __sincosf(a, &s1, &c1);
                float ck = c1, sk = s1;
                cr[0] += c1; ci[0] += s1;
                #pragma unroll
                for (int k = 1; k < NPTS; ++k) {
                    float cn_ = ck * c1 - sk * s1;
                    float sn_ = sk * c1 + ck * s1;
                    ck = cn_; sk = sn_;
                    cr[k] += ck; ci[k] += sk;
                }
            }
        // reduce across the 4 quads sharing a column, then 16 lanes atomic
        #pragma unroll
        for (int k = 0; k < NPTS; ++k) {
            cr[k] += __shfl_down(cr[k], 32, 64); cr[k] += __shfl_down(cr[k], 16, 64);
            ci[k] += __shfl_down(ci[k], 32, 64); ci[k] += __shfl_down(ci[k], 16, 64);
        }
        if (lane < 16) {
            const int col = tn + wn * 64 + j * 16 + lane;
            #pragma unroll
            for (int k = 0; k < NPTS; ++k) {
                atomicAdd(&pecf[(size_t)(k * 2 + 0) * KDIR + col], cr[k]);
                atomicAdd(&pecf[(size_t)(k * 2 + 1) * KDIR + col], ci[k]);
            }
        }
    }

    __threadfence();
    cg::this_grid().sync();

    // final: block (0,0) reduces 17x512 integrand terms -> out[0]
    if (blockIdx.x == 0 && blockIdx.y == 0) {
        double local = 0.0;
        for (int p = tid; p < NPTS * KDIR; p += 256) {
            const int i = p >> 9;          // p / 512
            const int c = p & 511;
            float fr = __hip_atomic_load(&pecf[(size_t)(i * 2 + 0) * KDIR + c],
                                         __ATOMIC_RELAXED, __HIP_MEMORY_SCOPE_AGENT);
            float fi = __hip_atomic_load(&pecf[(size_t)(i * 2 + 1) * KDIR + c],
                                         __ATOMIC_RELAXED, __HIP_MEMORY_SCOPE_AGENT);
            const double R = (double)fr / (double)BATCH;
            const double I = (double)fi / (double)BATCH;
            const double t = (2.0 / 17.0) * (double)(i + 1);
            const double tau = exp(-0.5 * t * t);
            const double w = (i == 0 || i == NPTS - 1) ? (1.0 / 17.0) : (2.0 / 17.0);
            const double dR = R - tau;
            local += w * (dR * dR + I * I);
        }
        __shared__ double red[256];
        red[tid] = local;
        __syncthreads();
        for (int s = 128; s > 0; s >>= 1) {
            if (tid < s) red[tid] += red[tid + s];
            __syncthreads();
        }
        if (tid == 0) out[0] = (float)(red[0] / (double)KDIR);
    }
}

// ---------------------------------------------------------------------------
extern "C" void kernel_launch(void* const* d_in, const int* in_sizes, int n_in,
                              void* d_out, int out_size, void* d_ws, size_t ws_size,
                              hipStream_t stream) {
    const float* emb = (const float*)d_in[0];   // (8192, 2048) fp32
    const float* dir = (const float*)d_in[1];   // (2048, 512) fp32
    float* out = (float*)d_out;

    char* ws = (char*)d_ws;
    _Float16* A16  = (_Float16*)(ws + 0);               // 33,554,432 B
    _Float16* dT   = (_Float16*)(ws + 33554432);        //  2,097,152 B
    float*    pp   = (float*)   (ws + 35651584);        //      4,096 B
    float*    pecf = (float*)   (ws + 35655680);        //     69,632 B

    norm_dT<<<KDIR, 256, 0, stream>>>(dir, dT, pp, pecf);
    cvt_f16<<<(BATCH * DIM) / (256 * 8), 256, 0, stream>>>(emb, A16);

    const _Float16* A16c = A16;
    const _Float16* dTc  = dT;
    void* args[] = {(void*)&A16c, (void*)&dTc, (void*)&pp, (void*)&pecf, (void*)&out};
    hipLaunchCooperativeKernel((const void*)megak, dim3(BATCH / 128, KDIR / 128),
                               dim3(256), args, 0, stream);
}

// Round 9
// 169.099 us; speedup vs baseline: 1.6948x; 1.6948x over previous
//
#include <hip/hip_runtime.h>
#include <hip/hip_bf16.h>
#include <stdint.h>
#include <math.h>

// Problem constants (fixed by setup_inputs)
#define BATCH 8192   // B rows of embeddings
#define DIM   2048   // D feature dim
#define KDIR  512    // K directions
#define NPTS  17     // quadrature points

typedef _Float16 half8  __attribute__((ext_vector_type(8)));
typedef float   floatx4 __attribute__((ext_vector_type(4)));

#define AS1 __attribute__((address_space(1)))
#define AS3 __attribute__((address_space(3)))

// async global->LDS, 16B per lane. LDS dest must be wave-uniform base + lane*16.
__device__ __forceinline__ void g2l16(const void* g, void* l) {
    __builtin_amdgcn_global_load_lds((AS1 void*)(uintptr_t)g, (AS3 void*)l, 16u, 0, 0u);
}

// ---------------------------------------------------------------------------
// K1: fused normalize + transpose (+ zero pp/out in low blocks).
__global__ __launch_bounds__(256) void norm_dT(const float* __restrict__ dir,
                                               _Float16* __restrict__ dT,
                                               float* __restrict__ pp,
                                               float* __restrict__ out) {
    const int k = blockIdx.x;
    const int t = threadIdx.x;
    if (k < 4) pp[k * 256 + t] = 0.f;
    if (k == 4 && t == 0) out[0] = 0.f;

    float v[8];
    float s = 0.f;
    #pragma unroll
    for (int i = 0; i < 8; ++i) {
        v[i] = dir[(size_t)(t * 8 + i) * KDIR + k];
        s = fmaf(v[i], v[i], s);
    }
    for (int off = 32; off > 0; off >>= 1) s += __shfl_down(s, off, 64);
    __shared__ float ws_[4];
    if ((t & 63) == 0) ws_[t >> 6] = s;
    __syncthreads();
    const float inv = 1.0f / fmaxf(sqrtf(ws_[0] + ws_[1] + ws_[2] + ws_[3]), 1e-12f);
    half8 h;
    #pragma unroll
    for (int i = 0; i < 8; ++i) h[i] = (_Float16)(v[i] * inv);
    *(half8*)(dT + (size_t)k * DIM + t * 8) = h;
}

// ---------------------------------------------------------------------------
// K2: embeddings fp32 -> fp16
__global__ __launch_bounds__(256) void cvt_f16(const float* __restrict__ x,
                                               _Float16* __restrict__ y) {
    const size_t i = ((size_t)blockIdx.x * 256 + threadIdx.x) * 8;
    floatx4 a = *(const floatx4*)(x + i);
    floatx4 b = *(const floatx4*)(x + i + 4);
    half8 h;
    h[0] = (_Float16)a[0]; h[1] = (_Float16)a[1];
    h[2] = (_Float16)a[2]; h[3] = (_Float16)a[3];
    h[4] = (_Float16)b[0]; h[5] = (_Float16)b[1];
    h[6] = (_Float16)b[2]; h[7] = (_Float16)b[3];
    *(half8*)(y + i) = h;
}

// ---------------------------------------------------------------------------
// K3: fp16 MFMA GEMM (R6's measured-45.8us version, byte-identical).
__global__ __launch_bounds__(256) void gemm16(const _Float16* __restrict__ A,
                                              const _Float16* __restrict__ Bt,
                                              float* __restrict__ C,
                                              float* __restrict__ pp) {
    __shared__ _Float16 sA[2][2][128 * 32];   // [stage][panel][m][k] 8KB each
    __shared__ _Float16 sB[2][2][128 * 32];

    const int tid  = threadIdx.x;
    const int lane = tid & 63;
    const int wave = tid >> 6;
    const int wm = wave & 1;
    const int wn = wave >> 1;
    const int tm = blockIdx.x * 128;
    const int tn = blockIdx.y * 128;

    const int srow = tid >> 2;
    const int scol = (tid & 3) * 8;
    const _Float16* baseA = A  + (size_t)(tm + srow) * DIM + scol;
    const _Float16* baseB = Bt + (size_t)(tn + srow) * DIM + scol;

#define ISSUE(IT, ST)                                                         \
    do {                                                                      \
        const _Float16* pa = baseA + (IT) * 64;                               \
        const _Float16* pb = baseB + (IT) * 64;                               \
        g2l16(pa,                 (char*)&sA[ST][0][0] + tid * 16);           \
        g2l16(pa + 64 * DIM,      (char*)&sA[ST][0][0] + 4096 + tid * 16);    \
        g2l16(pa + 32,            (char*)&sA[ST][1][0] + tid * 16);           \
        g2l16(pa + 64 * DIM + 32, (char*)&sA[ST][1][0] + 4096 + tid * 16);    \
        g2l16(pb,                 (char*)&sB[ST][0][0] + tid * 16);           \
        g2l16(pb + 64 * DIM,      (char*)&sB[ST][0][0] + 4096 + tid * 16);    \
        g2l16(pb + 32,            (char*)&sB[ST][1][0] + tid * 16);           \
        g2l16(pb + 64 * DIM + 32, (char*)&sB[ST][1][0] + 4096 + tid * 16);    \
    } while (0)

    const floatx4 zero = {0.f, 0.f, 0.f, 0.f};
    floatx4 acc[4][4];
    #pragma unroll
    for (int i = 0; i < 4; ++i)
        #pragma unroll
        for (int j = 0; j < 4; ++j) acc[i][j] = zero;

    const int mrow = lane & 15;
    const int kk   = (lane >> 4) * 8;

    ISSUE(0, 0);

    const int NIT = DIM / 64;                      // 32
    for (int it = 0; it < NIT; ++it) {
        const int s = it & 1;
        if (it + 1 < NIT) {
            ISSUE(it + 1, (it + 1) & 1);
            asm volatile("s_waitcnt vmcnt(8)" ::: "memory");
        } else {
            asm volatile("s_waitcnt vmcnt(0)" ::: "memory");
        }
        asm volatile("s_barrier" ::: "memory");

        half8 a0[4], a1[4], b0[4], b1[4];
        #pragma unroll
        for (int f = 0; f < 4; ++f) {
            a0[f] = *(const half8*)(&sA[s][0][(size_t)(wm * 64 + f * 16 + mrow) * 32 + kk]);
            a1[f] = *(const half8*)(&sA[s][1][(size_t)(wm * 64 + f * 16 + mrow) * 32 + kk]);
            b0[f] = *(const half8*)(&sB[s][0][(size_t)(wn * 64 + f * 16 + mrow) * 32 + kk]);
            b1[f] = *(const half8*)(&sB[s][1][(size_t)(wn * 64 + f * 16 + mrow) * 32 + kk]);
        }
        #pragma unroll
        for (int i = 0; i < 4; ++i)
            #pragma unroll
            for (int j = 0; j < 4; ++j) {
                acc[i][j] = __builtin_amdgcn_mfma_f32_16x16x32_f16(a0[i], b0[j], acc[i][j], 0, 0, 0);
                acc[i][j] = __builtin_amdgcn_mfma_f32_16x16x32_f16(a1[i], b1[j], acc[i][j], 0, 0, 0);
            }
        asm volatile("s_waitcnt lgkmcnt(0)" ::: "memory");
        asm volatile("s_barrier" ::: "memory");
    }
#undef ISSUE

    // C/D layout: col = lane&15, row = (lane>>4)*4 + reg
    const int r0 = (lane >> 4) * 4;
    const int cn = lane & 15;
    #pragma unroll
    for (int i = 0; i < 4; ++i) {
        #pragma unroll
        for (int j = 0; j < 4; ++j) {
            const int row = tm + wm * 64 + i * 16 + r0;
            const int col = tn + wn * 64 + j * 16 + cn;
            #pragma unroll
            for (int r = 0; r < 4; ++r)
                C[(size_t)(row + r) * KDIR + col] = acc[i][j][r];
        }
    }

    // fused column stats
    #pragma unroll
    for (int j = 0; j < 4; ++j) {
        float s = 0.f, q = 0.f;
        #pragma unroll
        for (int i = 0; i < 4; ++i)
            #pragma unroll
            for (int r = 0; r < 4; ++r) {
                float v = acc[i][j][r];
                s += v;
                q = fmaf(v, v, q);
            }
        s += __shfl_down(s, 32, 64); q += __shfl_down(q, 32, 64);
        s += __shfl_down(s, 16, 64); q += __shfl_down(q, 16, 64);
        if (lane < 16) {
            const int col = tn + wn * 64 + j * 16 + lane;
            atomicAdd(&pp[col], s);
            atomicAdd(&pp[KDIR + col], q);
        }
    }
}

// ---------------------------------------------------------------------------
// K4: ECF partials; mu/isd inline from pp. 32 rows/chunk -> 256 chunks x 2
// halves = 512 blocks. Chebyshev 3-term recurrence: cos/sin(k·a) each cost
// 1 FMA per k (vs 2 ops for angle-addition) -> ~27% fewer VALU ops.
__global__ __launch_bounds__(256) void ecf_p1(const float* __restrict__ proj,
                                              const float* __restrict__ pp,
                                              float* __restrict__ pecf) {
    const int ch = blockIdx.x >> 1;                      // 0..255
    const int c  = (blockIdx.x & 1) * 256 + threadIdx.x; // 0..511
    const double s_  = (double)pp[c];
    const double s2_ = (double)pp[KDIR + c];
    const double mm  = s_ / (double)BATCH;
    const double var = (s2_ - (double)BATCH * mm * mm) / (double)(BATCH - 1);
    const float m   = (float)mm;
    const float sdi = (float)(1.0 / (sqrt(var) + 1e-8));

    float cr[NPTS], ci[NPTS];
    #pragma unroll
    for (int i = 0; i < NPTS; ++i) { cr[i] = 0.f; ci[i] = 0.f; }
    const float* p = proj + (size_t)(ch * 32) * KDIR + c;
    #pragma unroll 8
    for (int r = 0; r < 32; ++r) {
        float z = (p[(size_t)r * KDIR] - m) * sdi;
        float a = z * (2.0f / 17.0f);                    // t_1 * z
        float s1, c1;
        __sincosf(a, &s1, &c1);
        const float tc = 2.0f * c1;
        float cm = 1.0f, sm = 0.0f;                      // cos(0), sin(0)
        float ck = c1,  sk = s1;                         // cos(a), sin(a)
        cr[0] += ck; ci[0] += sk;
        #pragma unroll
        for (int k = 1; k < NPTS; ++k) {
            float cn_ = fmaf(tc, ck, -cm);
            float sn_ = fmaf(tc, sk, -sm);
            cm = ck; sm = sk;
            ck = cn_; sk = sn_;
            cr[k] += ck; ci[k] += sk;
        }
    }
    #pragma unroll
    for (int i = 0; i < NPTS; ++i) {
        pecf[(size_t)((ch * NPTS + i) * 2 + 0) * KDIR + c] = cr[i];
        pecf[(size_t)((ch * NPTS + i) * 2 + 1) * KDIR + c] = ci[i];
    }
}

// K5: chunk reduce, one latency round: 544 blocks = 17 i x 16 grp x 2 halves.
__global__ __launch_bounds__(256) void ecf_p2a(const float* __restrict__ pecf,
                                               double* __restrict__ pec2) {
    const int b = blockIdx.x;
    const int i = b >> 5;                 // 0..16
    const int r = b & 31;
    const int g = r >> 1;                 // 0..15 (16 chunks each)
    const int half = r & 1;
    const int c = half * 256 + threadIdx.x;
    double sc = 0.0, ss = 0.0;
    #pragma unroll
    for (int k = 0; k < 16; ++k) {
        const int ch = g * 16 + k;
        sc += (double)pecf[(size_t)((ch * NPTS + i) * 2 + 0) * KDIR + c];
        ss += (double)pecf[(size_t)((ch * NPTS + i) * 2 + 1) * KDIR + c];
    }
    pec2[(size_t)((i * 16 + g) * 2 + 0) * KDIR + c] = sc;
    pec2[(size_t)((i * 16 + g) * 2 + 1) * KDIR + c] = ss;
}

// K6: finish: sum 16 groups (unrolled), integrand, block-reduce, atomic.
__global__ __launch_bounds__(256) void ecf_p2b(const double* __restrict__ pec2,
                                               float* __restrict__ out) {
    const int i = blockIdx.x >> 1;
    const int c = (blockIdx.x & 1) * 256 + threadIdx.x;
    double sc = 0.0, ss = 0.0;
    #pragma unroll
    for (int g = 0; g < 16; ++g) {
        sc += pec2[(size_t)((i * 16 + g) * 2 + 0) * KDIR + c];
        ss += pec2[(size_t)((i * 16 + g) * 2 + 1) * KDIR + c];
    }
    const double R = sc / (double)BATCH;
    const double I = ss / (double)BATCH;
    const double t = (2.0 / 17.0) * (double)(i + 1);
    const double tau = exp(-0.5 * t * t);
    const double w = (i == 0 || i == NPTS - 1) ? (1.0 / 17.0) : (2.0 / 17.0);
    const double dR = R - tau;
    double contrib = w * (dR * dR + I * I) / (double)KDIR;

    __shared__ double red[256];
    red[threadIdx.x] = contrib;
    __syncthreads();
    for (int s = 128; s > 0; s >>= 1) {
        if (threadIdx.x < s) red[threadIdx.x] += red[threadIdx.x + s];
        __syncthreads();
    }
    if (threadIdx.x == 0) atomicAdd(out, (float)red[0]);
}

// ---------------------------------------------------------------------------
extern "C" void kernel_launch(void* const* d_in, const int* in_sizes, int n_in,
                              void* d_out, int out_size, void* d_ws, size_t ws_size,
                              hipStream_t stream) {
    const float* emb = (const float*)d_in[0];   // (8192, 2048) fp32
    const float* dir = (const float*)d_in[1];   // (2048, 512) fp32
    float* out = (float*)d_out;

    char* ws = (char*)d_ws;
    // pecf/pec2 alias the A16 region (dead after GEMM).
    _Float16* A16  = (_Float16*)(ws + 0);               // 33,554,432 B
    float*    pecf = (float*)   (ws + 0);               // 17,825,792 B (after GEMM)
    double*   pec2 = (double*)  (ws + 17825792);        //  2,228,224 B (after GEMM)
    _Float16* dT   = (_Float16*)(ws + 33554432);        //  2,097,152 B
    float*    proj = (float*)   (ws + 35651584);        // 16,777,216 B
    float*    pp   = (float*)   (ws + 52428800);        //      4,096 B

    norm_dT<<<KDIR, 256, 0, stream>>>(dir, dT, pp, out);
    cvt_f16<<<(BATCH * DIM) / (256 * 8), 256, 0, stream>>>(emb, A16);
    gemm16<<<dim3(BATCH / 128, KDIR / 128), 256, 0, stream>>>(A16, dT, proj, pp);
    ecf_p1<<<512, 256, 0, stream>>>(proj, pp, pecf);
    ecf_p2a<<<544, 256, 0, stream>>>(pecf, pec2);
    ecf_p2b<<<34, 256, 0, stream>>>(pec2, out);
}

// Round 10
// 166.881 us; speedup vs baseline: 1.7173x; 1.0133x over previous
//
#include <hip/hip_runtime.h>
#include <hip/hip_bf16.h>
#include <stdint.h>
#include <math.h>

// Problem constants (fixed by setup_inputs)
#define BATCH 8192   // B rows of embeddings
#define DIM   2048   // D feature dim
#define KDIR  512    // K directions
#define NPTS  17     // quadrature points

typedef _Float16 half8  __attribute__((ext_vector_type(8)));
typedef float   floatx4 __attribute__((ext_vector_type(4)));

#define AS1 __attribute__((address_space(1)))
#define AS3 __attribute__((address_space(3)))

// async global->LDS, 16B per lane. LDS dest must be wave-uniform base + lane*16.
__device__ __forceinline__ void g2l16(const void* g, void* l) {
    __builtin_amdgcn_global_load_lds((AS1 void*)(uintptr_t)g, (AS3 void*)l, 16u, 0, 0u);
}

// ---------------------------------------------------------------------------
// K1: PREP. blocks [0,8192): emb fp32->fp16 (also zero pp/out in blocks 0-4).
//     blocks [8192,8256): normalize+transpose dir -> dT, 8 columns per block,
//     coalesced 32B row-chunk reads + LDS round-trip, coalesced half8 writes.
__global__ __launch_bounds__(256) void prep(const float* __restrict__ emb,
                                            const float* __restrict__ dir,
                                            _Float16* __restrict__ A16,
                                            _Float16* __restrict__ dT,
                                            float* __restrict__ pp,
                                            float* __restrict__ out) {
    const int b = blockIdx.x;
    const int t = threadIdx.x;
    if (b < 8192) {
        if (b < 4) pp[b * 256 + t] = 0.f;
        if (b == 4 && t == 0) out[0] = 0.f;
        const size_t i = ((size_t)b * 256 + t) * 8;
        floatx4 a = *(const floatx4*)(emb + i);
        floatx4 c = *(const floatx4*)(emb + i + 4);
        half8 h;
        h[0] = (_Float16)a[0]; h[1] = (_Float16)a[1];
        h[2] = (_Float16)a[2]; h[3] = (_Float16)a[3];
        h[4] = (_Float16)c[0]; h[5] = (_Float16)c[1];
        h[6] = (_Float16)c[2]; h[7] = (_Float16)c[3];
        *(half8*)(A16 + i) = h;
        return;
    }
    // norm blocks: 8 direction-columns per block
    const int k0 = (b - 8192) * 8;
    __shared__ _Float16 sv[8][2052];    // [col][row] staged values (fp16)
    __shared__ float    sred[8][32];
    __shared__ float    sinv[8];
    const int g  = t >> 3;     // 0..31 row-group
    const int cl = t & 7;      // col within 8
    float ss = 0.f;
    #pragma unroll 8
    for (int it = 0; it < 64; ++it) {
        const int r = it * 32 + g;
        float v = dir[(size_t)r * KDIR + k0 + cl];   // 8 lanes = 32B contiguous
        sv[cl][r] = (_Float16)v;
        ss = fmaf(v, v, ss);
    }
    sred[cl][g] = ss;
    __syncthreads();
    if (t < 8) {
        float s = 0.f;
        #pragma unroll
        for (int gg = 0; gg < 32; ++gg) s += sred[t][gg];
        sinv[t] = 1.0f / fmaxf(sqrtf(s), 1e-12f);
    }
    __syncthreads();
    // pass 2: coalesced half8 writes of dT rows
    const int c2 = t >> 5;     // 0..7 col
    const int p  = t & 31;
    const float inv = sinv[c2];
    #pragma unroll
    for (int it2 = 0; it2 < 8; ++it2) {
        const int i0 = p * 8 + it2 * 256;
        half8 h;
        #pragma unroll
        for (int e = 0; e < 8; ++e) h[e] = (_Float16)((float)sv[c2][i0 + e] * inv);
        *(half8*)(dT + (size_t)(k0 + c2) * DIM + i0) = h;
    }
}

// ---------------------------------------------------------------------------
// K2: fp16 MFMA GEMM (R6/R9's measured-45.6us structure; only change: fp16 C).
__global__ __launch_bounds__(256) void gemm16(const _Float16* __restrict__ A,
                                              const _Float16* __restrict__ Bt,
                                              _Float16* __restrict__ C,
                                              float* __restrict__ pp) {
    __shared__ _Float16 sA[2][2][128 * 32];   // [stage][panel][m][k] 8KB each
    __shared__ _Float16 sB[2][2][128 * 32];

    const int tid  = threadIdx.x;
    const int lane = tid & 63;
    const int wave = tid >> 6;
    const int wm = wave & 1;
    const int wn = wave >> 1;
    const int tm = blockIdx.x * 128;
    const int tn = blockIdx.y * 128;

    const int srow = tid >> 2;
    const int scol = (tid & 3) * 8;
    const _Float16* baseA = A  + (size_t)(tm + srow) * DIM + scol;
    const _Float16* baseB = Bt + (size_t)(tn + srow) * DIM + scol;

#define ISSUE(IT, ST)                                                         \
    do {                                                                      \
        const _Float16* pa = baseA + (IT) * 64;                               \
        const _Float16* pb = baseB + (IT) * 64;                               \
        g2l16(pa,                 (char*)&sA[ST][0][0] + tid * 16);           \
        g2l16(pa + 64 * DIM,      (char*)&sA[ST][0][0] + 4096 + tid * 16);    \
        g2l16(pa + 32,            (char*)&sA[ST][1][0] + tid * 16);           \
        g2l16(pa + 64 * DIM + 32, (char*)&sA[ST][1][0] + 4096 + tid * 16);    \
        g2l16(pb,                 (char*)&sB[ST][0][0] + tid * 16);           \
        g2l16(pb + 64 * DIM,      (char*)&sB[ST][0][0] + 4096 + tid * 16);    \
        g2l16(pb + 32,            (char*)&sB[ST][1][0] + tid * 16);           \
        g2l16(pb + 64 * DIM + 32, (char*)&sB[ST][1][0] + 4096 + tid * 16);    \
    } while (0)

    const floatx4 zero = {0.f, 0.f, 0.f, 0.f};
    floatx4 acc[4][4];
    #pragma unroll
    for (int i = 0; i < 4; ++i)
        #pragma unroll
        for (int j = 0; j < 4; ++j) acc[i][j] = zero;

    const int mrow = lane & 15;
    const int kk   = (lane >> 4) * 8;

    ISSUE(0, 0);

    const int NIT = DIM / 64;                      // 32
    for (int it = 0; it < NIT; ++it) {
        const int s = it & 1;
        if (it + 1 < NIT) {
            ISSUE(it + 1, (it + 1) & 1);
            asm volatile("s_waitcnt vmcnt(8)" ::: "memory");
        } else {
            asm volatile("s_waitcnt vmcnt(0)" ::: "memory");
        }
        asm volatile("s_barrier" ::: "memory");

        half8 a0[4], a1[4], b0[4], b1[4];
        #pragma unroll
        for (int f = 0; f < 4; ++f) {
            a0[f] = *(const half8*)(&sA[s][0][(size_t)(wm * 64 + f * 16 + mrow) * 32 + kk]);
            a1[f] = *(const half8*)(&sA[s][1][(size_t)(wm * 64 + f * 16 + mrow) * 32 + kk]);
            b0[f] = *(const half8*)(&sB[s][0][(size_t)(wn * 64 + f * 16 + mrow) * 32 + kk]);
            b1[f] = *(const half8*)(&sB[s][1][(size_t)(wn * 64 + f * 16 + mrow) * 32 + kk]);
        }
        #pragma unroll
        for (int i = 0; i < 4; ++i)
            #pragma unroll
            for (int j = 0; j < 4; ++j) {
                acc[i][j] = __builtin_amdgcn_mfma_f32_16x16x32_f16(a0[i], b0[j], acc[i][j], 0, 0, 0);
                acc[i][j] = __builtin_amdgcn_mfma_f32_16x16x32_f16(a1[i], b1[j], acc[i][j], 0, 0, 0);
            }
        asm volatile("s_waitcnt lgkmcnt(0)" ::: "memory");
        asm volatile("s_barrier" ::: "memory");
    }
#undef ISSUE

    // C/D layout: col = lane&15, row = (lane>>4)*4 + reg. fp16 stores.
    const int r0 = (lane >> 4) * 4;
    const int cn = lane & 15;
    #pragma unroll
    for (int i = 0; i < 4; ++i) {
        #pragma unroll
        for (int j = 0; j < 4; ++j) {
            const int row = tm + wm * 64 + i * 16 + r0;
            const int col = tn + wn * 64 + j * 16 + cn;
            #pragma unroll
            for (int r = 0; r < 4; ++r)
                C[(size_t)(row + r) * KDIR + col] = (_Float16)acc[i][j][r];
        }
    }

    // fused column stats (fp32 acc values)
    #pragma unroll
    for (int j = 0; j < 4; ++j) {
        float s = 0.f, q = 0.f;
        #pragma unroll
        for (int i = 0; i < 4; ++i)
            #pragma unroll
            for (int r = 0; r < 4; ++r) {
                float v = acc[i][j][r];
                s += v;
                q = fmaf(v, v, q);
            }
        s += __shfl_down(s, 32, 64); q += __shfl_down(q, 32, 64);
        s += __shfl_down(s, 16, 64); q += __shfl_down(q, 16, 64);
        if (lane < 16) {
            const int col = tn + wn * 64 + j * 16 + lane;
            atomicAdd(&pp[col], s);
            atomicAdd(&pp[KDIR + col], q);
        }
    }
}

// ---------------------------------------------------------------------------
// K3: ECF partials from fp16 proj; mu/isd inline from pp; Chebyshev recurrence.
__global__ __launch_bounds__(256) void ecf_p1(const _Float16* __restrict__ proj,
                                              const float* __restrict__ pp,
                                              float* __restrict__ pecf) {
    const int ch = blockIdx.x >> 1;                      // 0..255
    const int c  = (blockIdx.x & 1) * 256 + threadIdx.x; // 0..511
    const double s_  = (double)pp[c];
    const double s2_ = (double)pp[KDIR + c];
    const double mm  = s_ / (double)BATCH;
    const double var = (s2_ - (double)BATCH * mm * mm) / (double)(BATCH - 1);
    const float m   = (float)mm;
    const float sdi = (float)(1.0 / (sqrt(var) + 1e-8));

    float cr[NPTS], ci[NPTS];
    #pragma unroll
    for (int i = 0; i < NPTS; ++i) { cr[i] = 0.f; ci[i] = 0.f; }
    const _Float16* p = proj + (size_t)(ch * 32) * KDIR + c;
    #pragma unroll 8
    for (int r = 0; r < 32; ++r) {
        float z = ((float)p[(size_t)r * KDIR] - m) * sdi;
        float a = z * (2.0f / 17.0f);                    // t_1 * z
        float s1, c1;
        __sincosf(a, &s1, &c1);
        const float tc = 2.0f * c1;
        float cm = 1.0f, sm = 0.0f;
        float ck = c1,  sk = s1;
        cr[0] += ck; ci[0] += sk;
        #pragma unroll
        for (int k = 1; k < NPTS; ++k) {
            float cn_ = fmaf(tc, ck, -cm);
            float sn_ = fmaf(tc, sk, -sm);
            cm = ck; sm = sk;
            ck = cn_; sk = sn_;
            cr[k] += ck; ci[k] += sk;
        }
    }
    #pragma unroll
    for (int i = 0; i < NPTS; ++i) {
        pecf[(size_t)((ch * NPTS + i) * 2 + 0) * KDIR + c] = cr[i];
        pecf[(size_t)((ch * NPTS + i) * 2 + 1) * KDIR + c] = ci[i];
    }
}

// K4: chunk reduce, one latency round: 544 blocks = 17 i x 16 grp x 2 halves.
__global__ __launch_bounds__(256) void ecf_p2a(const float* __restrict__ pecf,
                                               double* __restrict__ pec2) {
    const int b = blockIdx.x;
    const int i = b >> 5;                 // 0..16
    const int r = b & 31;
    const int g = r >> 1;                 // 0..15 (16 chunks each)
    const int half = r & 1;
    const int c = half * 256 + threadIdx.x;
    double sc = 0.0, ss = 0.0;
    #pragma unroll
    for (int k = 0; k < 16; ++k) {
        const int ch = g * 16 + k;
        sc += (double)pecf[(size_t)((ch * NPTS + i) * 2 + 0) * KDIR + c];
        ss += (double)pecf[(size_t)((ch * NPTS + i) * 2 + 1) * KDIR + c];
    }
    pec2[(size_t)((i * 16 + g) * 2 + 0) * KDIR + c] = sc;
    pec2[(size_t)((i * 16 + g) * 2 + 1) * KDIR + c] = ss;
}

// K5: finish: sum 16 groups, integrand, block-reduce, atomic.
__global__ __launch_bounds__(256) void ecf_p2b(const double* __restrict__ pec2,
                                               float* __restrict__ out) {
    const int i = blockIdx.x >> 1;
    const int c = (blockIdx.x & 1) * 256 + threadIdx.x;
    double sc = 0.0, ss = 0.0;
    #pragma unroll
    for (int g = 0; g < 16; ++g) {
        sc += pec2[(size_t)((i * 16 + g) * 2 + 0) * KDIR + c];
        ss += pec2[(size_t)((i * 16 + g) * 2 + 1) * KDIR + c];
    }
    const double R = sc / (double)BATCH;
    const double I = ss / (double)BATCH;
    const double t = (2.0 / 17.0) * (double)(i + 1);
    const double tau = exp(-0.5 * t * t);
    const double w = (i == 0 || i == NPTS - 1) ? (1.0 / 17.0) : (2.0 / 17.0);
    const double dR = R - tau;
    double contrib = w * (dR * dR + I * I) / (double)KDIR;

    __shared__ double red[256];
    red[threadIdx.x] = contrib;
    __syncthreads();
    for (int s = 128; s > 0; s >>= 1) {
        if (threadIdx.x < s) red[threadIdx.x] += red[threadIdx.x + s];
        __syncthreads();
    }
    if (threadIdx.x == 0) atomicAdd(out, (float)red[0]);
}

// ---------------------------------------------------------------------------
extern "C" void kernel_launch(void* const* d_in, const int* in_sizes, int n_in,
                              void* d_out, int out_size, void* d_ws, size_t ws_size,
                              hipStream_t stream) {
    const float* emb = (const float*)d_in[0];   // (8192, 2048) fp32
    const float* dir = (const float*)d_in[1];   // (2048, 512) fp32
    float* out = (float*)d_out;

    char* ws = (char*)d_ws;
    // pecf/pec2 alias the A16 region (dead after GEMM).
    _Float16* A16  = (_Float16*)(ws + 0);               // 33,554,432 B
    float*    pecf = (float*)   (ws + 0);               // 17,825,792 B (after GEMM)
    double*   pec2 = (double*)  (ws + 17825792);        //  2,228,224 B (after GEMM)
    _Float16* dT   = (_Float16*)(ws + 33554432);        //  2,097,152 B
    _Float16* proj = (_Float16*)(ws + 35651584);        //  8,388,608 B
    float*    pp   = (float*)   (ws + 44040192);        //      4,096 B

    prep<<<8256, 256, 0, stream>>>(emb, dir, A16, dT, pp, out);
    gemm16<<<dim3(BATCH / 128, KDIR / 128), 256, 0, stream>>>(A16, dT, proj, pp);
    ecf_p1<<<512, 256, 0, stream>>>(proj, pp, pecf);
    ecf_p2a<<<544, 256, 0, stream>>>(pecf, pec2);
    ecf_p2b<<<34, 256, 0, stream>>>(pec2, out);
}